// Round 18
// baseline (336.197 us; speedup 1.0000x reference)
//
#include <hip/hip_runtime.h>

#define N_ROWS 65536
#define K_CODES 4096
#define D_DIM 256
#define MARGIN_BF 6.0e-5f
#define CAP_DUEL 24576
#define CAP_FULL 8192

typedef __attribute__((ext_vector_type(8))) _Float16 f16x8;
typedef __attribute__((ext_vector_type(4))) float f32x4;

typedef __attribute__((address_space(1))) unsigned int g_u32;
typedef __attribute__((address_space(3))) unsigned int l_u32;
// async global->LDS, 16B per lane; LDS dest = wave-uniform base + lane*16
#define GLOAD16(gp, lp) __builtin_amdgcn_global_load_lds((g_u32*)(gp), (l_u32*)(lp), 16, 0, 0)

// ---------------- ws layout ----------------
// [262144]   float  cvec[4096]           16 KB
// [278528]   ushort emb_perm[4096*256]    2 MB   (f16 x4096, pair-major stream-linear)
// [2375680]  int    cnts[2]  (0=duel, 1=full)
// [2375936]  int    fulllist[8192]       32 KB
// [2408704]  u64    duellist[24576]     192 KB
// [2605312]  u64    rescored[65536]     512 KB
// [3129600]  double partials[2048]       16 KB

union f16u { _Float16 h; unsigned short u; };

static __device__ __forceinline__ unsigned int pack2(float a, float b) {
    f16u x, y; x.h = (_Float16)a; y.h = (_Float16)b;
    return (unsigned)x.u | ((unsigned)y.u << 16);
}

// ---------------- r2-verified norm chain (verbatim body, block-offset) ----------------
static __device__ __forceinline__ void norm_body(const float* __restrict__ src,
                                                 float* __restrict__ dst, int bi, int tid) {
    int row = bi * 64 + (tid >> 2);
    int q = tid & 3;
    const float* p = src + (size_t)row * D_DIM;
    double acc = 0.0;
#pragma unroll 4
    for (int it = 0; it < 16; ++it) {
        float4 v = *(const float4*)&p[(q + 4 * it) * 4];
        float a = v.x * v.x, b = v.y * v.y, c = v.z * v.z, d = v.w * v.w;
        acc += (double)a; acc += (double)b; acc += (double)c; acc += (double)d;
    }
    acc += __shfl_xor(acc, 1);
    acc += __shfl_xor(acc, 2);
    if (q == 0) dst[row] = (float)acc;
}

// ---------------- emb -> f16(x4096) pair-major + emb-norm + cnt/rescored clear ----------------
// frag f = (h*512 + step*8 + d8)*2 + cf ; lane part holds
// emb[h*2048 + step*32 + cf*16 + (lane&15)][d8*32 + (lane>>4)*8 + 0..7] * 4096
__global__ __launch_bounds__(256) void cvt_emb_kernel(const float* __restrict__ emb,
                                                      unsigned short* __restrict__ emb_perm,
                                                      float* __restrict__ cvec,
                                                      int* __restrict__ cnts,
                                                      unsigned long long* __restrict__ rescored) {
    if (blockIdx.x >= 512) {
        if (blockIdx.x == 512 && threadIdx.x < 2) cnts[threadIdx.x] = 0;
        norm_body(emb, cvec, blockIdx.x - 512, threadIdx.x);
        return;
    }
    if (blockIdx.x < 256) rescored[blockIdx.x * 256 + threadIdx.x] = ~0ull;
    int gid = blockIdx.x * 256 + threadIdx.x;     // 131072 16B units
    int lane = gid & 63;
    int f = gid >> 6;
    int cf = f & 1;
    int d8 = (f >> 1) & 7;
    int step = (f >> 4) & 63;
    int h = f >> 10;
    int code = h * 2048 + step * 32 + cf * 16 + (lane & 15);
    int d0 = d8 * 32 + (lane >> 4) * 8;
    const float* p = emb + (size_t)code * D_DIM + d0;
    float4 v0 = *(const float4*)p;
    float4 v1 = *(const float4*)(p + 4);
    uint4 o;
    o.x = pack2(v0.x * 4096.0f, v0.y * 4096.0f);
    o.y = pack2(v0.z * 4096.0f, v0.w * 4096.0f);
    o.z = pack2(v1.x * 4096.0f, v1.y * 4096.0f);
    o.w = pack2(v1.z * 4096.0f, v1.w * 4096.0f);
    *(uint4*)((char*)emb_perm + (size_t)gid * 16) = o;
}

// ---------------- phase B: 64-row blocks (3/CU resident) + twin-wave ring + packed top-3 ----------------
// Block = 4 waves = 2 row-halves (pp: 32 rows, A converted f32->f16 in-register)
// x 2 code-halves (h). Shared 8-slot ring per h; counted vmcnt(5) + raw s_barrier (T4).
__global__ __launch_bounds__(256, 3) void phaseB_kernel(
        const float* __restrict__ z, const unsigned short* __restrict__ emb_perm,
        const float* __restrict__ cvec, float* __restrict__ out_idx,
        int* __restrict__ cnts, int* __restrict__ fulllist,
        unsigned long long* __restrict__ duellist) {
    __shared__ float cv[4096];                    // 16 KB cvec table; merge scratch after loop
    __shared__ unsigned short ring[2][8][1024];   // 32 KB: [h][slot][2KB pair]

    const int tid = threadIdx.x;
    const int lane = tid & 63;
    const int w = tid >> 6;
    const int pp = w >> 1;         // row half (also: which cf half this wave stages)
    const int h = w & 1;           // code half
    const int l15 = lane & 15, l4 = lane >> 4;
    const int rb = blockIdx.x;     // 1024 blocks x 64 rows

    // ---- cvec -> LDS ----
#pragma unroll
    for (int i = 0; i < 4; ++i) {
        int idx = i * 1024 + tid * 4;
        *(float4*)&cv[idx] = *(const float4*)&cvec[idx];
    }

    // ---- A: raw f32 z -> f16 frags in-register (r11-verified pack order) ----
    // A[d8][rf] lane part = z[rb*64 + pp*32 + rf*16 + l15][d8*32 + l4*8 + 0..7]
    f16x8 A[8][2];
    {
        union { f16x8 v; unsigned u[4]; } cvt;
        const float* zr = z + ((size_t)(rb * 64 + pp * 32 + l15)) * D_DIM + l4 * 8;
#pragma unroll
        for (int d8 = 0; d8 < 8; ++d8)
#pragma unroll
            for (int rf = 0; rf < 2; ++rf) {
                const float* p = zr + rf * 16 * D_DIM + d8 * 32;
                float4 v0 = *(const float4*)p;
                float4 v1 = *(const float4*)(p + 4);
                cvt.u[0] = pack2(v0.x, v0.y);
                cvt.u[1] = pack2(v0.z, v0.w);
                cvt.u[2] = pack2(v1.x, v1.y);
                cvt.u[3] = pack2(v1.z, v1.w);
                A[d8][rf] = cvt.v;
            }
    }
    __syncthreads();               // cv ready + vmcnt(0) drain: clean VM FIFO

    // ---- B ring setup: pair q at bsrc + q*2048 (this wave's cf=pp frag) ----
    const char* bsrc = (const char*)emb_perm + (size_t)h * 1048576 + pp * 1024 + lane * 16;
    char* ldst = (char*)&ring[h][0][0] + pp * 1024;        // uniform LDS dest base
    const char* lrd = (const char*)&ring[h][0][0] + lane * 16;

    // prologue: stage pairs 0..5 (depth 6)
#pragma unroll
    for (int q = 0; q < 6; ++q)
        GLOAD16(bsrc + q * 2048, ldst + q * 2048);
    asm volatile("s_waitcnt vmcnt(5)" ::: "memory");       // my pair-0 half landed
    __builtin_amdgcn_s_barrier();                          // partner's half landed too
    __builtin_amdgcn_sched_barrier(0);

    f16x8 B0a = *(const f16x8*)(lrd);                      // pair 0, cf0
    f16x8 B0b = *(const f16x8*)(lrd + 1024);               // pair 0, cf1
    f16x8 B1a, B1b;

    float m1[8], m2[8], m3[8];     // index-packed distances
#pragma unroll
    for (int t = 0; t < 8; ++t) { m1[t] = 3.4e38f; m2[t] = 3.4e38f; m3[t] = 3.4e38f; }

    f32x4 acc[2][2];

    for (int step = 0; step < 64; ++step) {
        const int kb = h * 2048 + step * 32;
        float ck0 = cv[kb + l15];
        float ck1 = cv[kb + 16 + l15];
#pragma unroll
        for (int rf = 0; rf < 2; ++rf) {
            acc[rf][0] = (f32x4){0.f, 0.f, 0.f, 0.f};
            acc[rf][1] = (f32x4){0.f, 0.f, 0.f, 0.f};
        }
#pragma unroll
        for (int d8 = 0; d8 < 8; ++d8) {
            // k = step*8 + d8. Stage pair k+6 into slot (d8+6)&7 (tail wraps to
            // pairs 0..5: re-stages dead slots with valid addrs, keeps counts uniform).
            {
                const char* g = bsrc + (size_t)(step * 8 + d8 + 6) * 2048
                                - ((step == 63 && d8 >= 2) ? 1048576 : 0);
                GLOAD16(g, ldst + ((d8 + 6) & 7) * 2048);
            }
            asm volatile("s_waitcnt vmcnt(5)" ::: "memory");   // pair k+1 (mine) landed
            __builtin_amdgcn_s_barrier();                      // partner's half landed
            __builtin_amdgcn_sched_barrier(0);
            // ds_read pair k+1 into reg slot (d8+1)&1 (lgkm hides across next iter)
            {
                const char* rp = lrd + ((d8 + 1) & 7) * 2048;
                if ((d8 + 1) & 1) { B1a = *(const f16x8*)rp; B1b = *(const f16x8*)(rp + 1024); }
                else              { B0a = *(const f16x8*)rp; B0b = *(const f16x8*)(rp + 1024); }
            }
            f16x8 b0 = (d8 & 1) ? B1a : B0a;   // pair k from slot d8&1
            f16x8 b1 = (d8 & 1) ? B1b : B0b;
#pragma unroll
            for (int rf = 0; rf < 2; ++rf) {
                acc[rf][0] = __builtin_amdgcn_mfma_f32_16x16x32_f16(A[d8][rf], b0, acc[rf][0], 0, 0, 0);
                acc[rf][1] = __builtin_amdgcn_mfma_f32_16x16x32_f16(A[d8][rf], b1, acc[rf][1], 0, 0, 0);
            }
        }

        // ---- epilogue: index-packed running top-3 over this step's 32 codes (r15-verified) ----
#pragma unroll
        for (int cf = 0; cf < 2; ++cf) {
            const float ck = cf ? ck1 : ck0;
            const unsigned cg = (unsigned)(kb + cf * 16 + l15);
#pragma unroll
            for (int rf = 0; rf < 2; ++rf)
#pragma unroll
                for (int j = 0; j < 4; ++j) {
                    // acc = z.(4096 e); -2*dot = acc * -2^-11 (exact scale)
                    float d = fmaf(-4.8828125e-4f, acc[rf][cf][j], ck);
                    float dp = __uint_as_float((__float_as_uint(d) & 0xfffff000u) | cg);
                    const int t = rf * 4 + j;
                    m3[t] = __builtin_amdgcn_fmed3f(dp, m2[t], m3[t]);
                    m2[t] = __builtin_amdgcn_fmed3f(dp, m1[t], m2[t]);
                    m1[t] = fminf(m1[t], dp);
                }
        }
    }

    // ---- per-wave merge across the 16 column-lanes (sorted-triple merge, r15-verified) ----
    __syncthreads();               // cv dead; reuse as merge scratch
    float* m1s = cv;               // [4][32]
    float* m2s = cv + 128;
    float* m3s = cv + 256;
#pragma unroll
    for (int t = 0; t < 8; ++t) {
        float a1 = m1[t], a2 = m2[t], a3 = m3[t];
        for (int msk = 8; msk >= 1; msk >>= 1) {
            float b1 = __shfl_xor(a1, msk);
            float b2 = __shfl_xor(a2, msk);
            float b3 = __shfl_xor(a3, msk);
            bool bw = b1 < a1;
            float w1 = bw ? b1 : a1, w2 = bw ? b2 : a2, w3 = bw ? b3 : a3;
            float l1 = bw ? a1 : b1, l2 = bw ? a2 : b2;
            bool t2 = l1 < w2;
            a1 = w1;
            a2 = t2 ? l1 : w2;
            a3 = t2 ? fminf(w2, l2) : fminf(w3, l1);
        }
        if (l15 == 0) {
            int rloc = (t >> 2) * 16 + l4 * 4 + (t & 3);   // rf*16 + l4*4 + j, 0..31
            m1s[w * 32 + rloc] = a1;
            m2s[w * 32 + rloc] = a2;
            m3s[w * 32 + rloc] = a3;
        }
    }
    __syncthreads();

    // ---- cross-wave merge (two code halves per row-half) + flag taxonomy ----
    if (tid < 64) {
        int pg = tid >> 5, rr = tid & 31;      // row-half, row within half
        int wA = pg * 2, wB = pg * 2 + 1;      // h=0, h=1 waves of this row-half
        float a1 = m1s[wA * 32 + rr], a2 = m2s[wA * 32 + rr], a3 = m3s[wA * 32 + rr];
        float b1 = m1s[wB * 32 + rr], b2 = m2s[wB * 32 + rr], b3 = m3s[wB * 32 + rr];
        bool bw = b1 < a1;
        float w1 = bw ? b1 : a1, w2 = bw ? b2 : a2, w3 = bw ? b3 : a3;
        float l1 = bw ? a1 : b1, l2 = bw ? a2 : b2;
        bool t2 = l1 < w2;
        float f1 = w1;
        float f2 = t2 ? l1 : w2;
        float f3 = t2 ? fminf(w2, l2) : fminf(w3, l1);

        int i1 = (int)(__float_as_uint(f1) & 0xfffu);
        int i2 = (int)(__float_as_uint(f2) & 0xfffu);
        int rowg = rb * 64 + pg * 32 + rr;
        out_idx[rowg] = (float)i1;
        if (f3 - f1 < MARGIN_BF) {                 // 3+ candidates: full exact rescan
            int pz = atomicAdd(&cnts[1], 1);
            if (pz < CAP_FULL) fulllist[pz] = rowg;
        } else if (f2 - f1 < MARGIN_BF) {          // exactly 2 candidates: exact duel
            int pz = atomicAdd(&cnts[0], 1);
            if (pz < CAP_DUEL) {
                duellist[pz] = ((unsigned long long)(unsigned)rowg << 32) |
                               ((unsigned)i1 << 16) | (unsigned)i2;
            } else {
                int pf = atomicAdd(&cnts[1], 1);
                if (pf < CAP_FULL) fulllist[pf] = rowg;
            }
        }
    }
}

// ---------------- exact duel: f32 chain (r2) on {i1,i2}; rownorm computed on the fly ----------------
__global__ __launch_bounds__(256) void duel_kernel(
        const float* __restrict__ z, const float* __restrict__ emb,
        const float* __restrict__ cvec,
        const int* __restrict__ cnts, const unsigned long long* __restrict__ duellist,
        unsigned long long* __restrict__ rescored) {
    int n = cnts[0];
    if (n > CAP_DUEL) n = CAP_DUEL;
    for (int i = blockIdx.x * 256 + threadIdx.x; i < n; i += 64 * 256) {
        unsigned long long e = duellist[i];
        int row = (int)(e >> 32);
        int c1 = (int)((e >> 16) & 0xfffu);
        int c2 = (int)(e & 0xfffu);
        const float* zp = z + (size_t)row * D_DIM;
        const float* p1 = emb + (size_t)c1 * D_DIM;
        const float* p2 = emb + (size_t)c2 * D_DIM;
        float a1 = 0.f, a2 = 0.f;
        double n0 = 0.0, n1 = 0.0, n2 = 0.0, n3 = 0.0;  // q-partials: r2-chain order
#pragma unroll 8
        for (int d4 = 0; d4 < 64; ++d4) {          // d ascending, xyzw: r2 chain
            float4 zf = *(const float4*)&zp[d4 * 4];
            float4 e1 = *(const float4*)&p1[d4 * 4];
            float4 e2 = *(const float4*)&p2[d4 * 4];
            a1 = fmaf(zf.x, e1.x, a1); a1 = fmaf(zf.y, e1.y, a1);
            a1 = fmaf(zf.z, e1.z, a1); a1 = fmaf(zf.w, e1.w, a1);
            a2 = fmaf(zf.x, e2.x, a2); a2 = fmaf(zf.y, e2.y, a2);
            a2 = fmaf(zf.z, e2.z, a2); a2 = fmaf(zf.w, e2.w, a2);
            float sx = zf.x * zf.x, sy = zf.y * zf.y, sz = zf.z * zf.z, sw = zf.w * zf.w;
            switch (d4 & 3) {                      // q = d4&3, it ascending: bit-exact r2 chain
                case 0: n0 += (double)sx; n0 += (double)sy; n0 += (double)sz; n0 += (double)sw; break;
                case 1: n1 += (double)sx; n1 += (double)sy; n1 += (double)sz; n1 += (double)sw; break;
                case 2: n2 += (double)sx; n2 += (double)sy; n2 += (double)sz; n2 += (double)sw; break;
                default: n3 += (double)sx; n3 += (double)sy; n3 += (double)sz; n3 += (double)sw; break;
            }
        }
        float rn = (float)((n0 + n1) + (n2 + n3));
        float d1 = __fadd_rn(__fsub_rn(rn, __fmul_rn(2.0f, a1)), cvec[c1]);
        float d2 = __fadd_rn(__fsub_rn(rn, __fmul_rn(2.0f, a2)), cvec[c2]);
        unsigned long long p1v = ((unsigned long long)__float_as_uint(d1) << 32) | (unsigned)c1;
        unsigned long long p2v = ((unsigned long long)__float_as_uint(d2) << 32) | (unsigned)c2;
        rescored[row] = p1v < p2v ? p1v : p2v;     // dist>0 -> f32 bits monotone
    }
}

// ---------------- full exact rescan (r2-chain); rownorm from staged zs ----------------
__global__ __launch_bounds__(256) void rescore_kernel(
        const float* __restrict__ z, const float* __restrict__ emb,
        const float* __restrict__ cvec,
        const int* __restrict__ cnts, const int* __restrict__ fulllist,
        unsigned long long* __restrict__ rescored) {
    __shared__ float zs[16][256];
    __shared__ float sa[16];
    __shared__ int srow[16];
    const int tid = threadIdx.x;
    int cnt = cnts[1];
    if (cnt > CAP_FULL) cnt = CAP_FULL;
    const int nu = ((cnt + 15) >> 4) << 2;   // ceil(cnt/16) row-groups x 4 code-splits
    for (int uu = blockIdx.x; uu < nu; uu += gridDim.x) {
        int rg = uu >> 2, ks = uu & 3;
        __syncthreads();
        if (tid < 16) {
            int fi = rg * 16 + tid;
            srow[tid] = fulllist[fi < cnt ? fi : 0];
        }
        __syncthreads();
#pragma unroll
        for (int i = 0; i < 4; ++i) {
            int u = i * 256 + tid;
            int r = u >> 6, d4 = u & 63;
            *(float4*)&zs[r][d4 * 4] = *(const float4*)&z[(size_t)srow[r] * D_DIM + d4 * 4];
        }
        __syncthreads();
        if (tid < 64) {                        // sa via r2 shfl-chain on staged zs
            int r = tid >> 2, q = tid & 3;
            double acc = 0.0;
#pragma unroll 4
            for (int it = 0; it < 16; ++it) {
                float4 v = *(const float4*)&zs[r][(q + 4 * it) * 4];
                float a = v.x * v.x, b = v.y * v.y, c = v.z * v.z, d = v.w * v.w;
                acc += (double)a; acc += (double)b; acc += (double)c; acc += (double)d;
            }
            acc += __shfl_xor(acc, 1);
            acc += __shfl_xor(acc, 2);
            if (q == 0) sa[r] = (float)acc;
        }
        __syncthreads();

        const int c0 = ks * 1024 + tid;
        float acc[16][4];
#pragma unroll
        for (int r = 0; r < 16; ++r)
#pragma unroll
            for (int j = 0; j < 4; ++j) acc[r][j] = 0.f;

        for (int ch = 0; ch < 8; ++ch) {
#pragma unroll
            for (int q = 0; q < 8; ++q) {
                float4 e0 = *(const float4*)&emb[(size_t)(c0      ) * D_DIM + ch * 32 + q * 4];
                float4 e1 = *(const float4*)&emb[(size_t)(c0 + 256) * D_DIM + ch * 32 + q * 4];
                float4 e2 = *(const float4*)&emb[(size_t)(c0 + 512) * D_DIM + ch * 32 + q * 4];
                float4 e3 = *(const float4*)&emb[(size_t)(c0 + 768) * D_DIM + ch * 32 + q * 4];
#pragma unroll
                for (int r = 0; r < 16; ++r) {
                    float4 zf = *(const float4*)&zs[r][ch * 32 + q * 4];
                    acc[r][0] = fmaf(zf.x, e0.x, acc[r][0]);
                    acc[r][0] = fmaf(zf.y, e0.y, acc[r][0]);
                    acc[r][0] = fmaf(zf.z, e0.z, acc[r][0]);
                    acc[r][0] = fmaf(zf.w, e0.w, acc[r][0]);
                    acc[r][1] = fmaf(zf.x, e1.x, acc[r][1]);
                    acc[r][1] = fmaf(zf.y, e1.y, acc[r][1]);
                    acc[r][1] = fmaf(zf.z, e1.z, acc[r][1]);
                    acc[r][1] = fmaf(zf.w, e1.w, acc[r][1]);
                    acc[r][2] = fmaf(zf.x, e2.x, acc[r][2]);
                    acc[r][2] = fmaf(zf.y, e2.y, acc[r][2]);
                    acc[r][2] = fmaf(zf.z, e2.z, acc[r][2]);
                    acc[r][2] = fmaf(zf.w, e2.w, acc[r][2]);
                    acc[r][3] = fmaf(zf.x, e3.x, acc[r][3]);
                    acc[r][3] = fmaf(zf.y, e3.y, acc[r][3]);
                    acc[r][3] = fmaf(zf.z, e3.z, acc[r][3]);
                    acc[r][3] = fmaf(zf.w, e3.w, acc[r][3]);
                }
            }
        }
        const float ck0 = cvec[c0], ck1 = cvec[c0 + 256];
        const float ck2 = cvec[c0 + 512], ck3 = cvec[c0 + 768];
#pragma unroll
        for (int r = 0; r < 16; ++r) {
            float d0 = __fadd_rn(__fsub_rn(sa[r], __fmul_rn(2.0f, acc[r][0])), ck0);
            float d1 = __fadd_rn(__fsub_rn(sa[r], __fmul_rn(2.0f, acc[r][1])), ck1);
            float d2 = __fadd_rn(__fsub_rn(sa[r], __fmul_rn(2.0f, acc[r][2])), ck2);
            float d3 = __fadd_rn(__fsub_rn(sa[r], __fmul_rn(2.0f, acc[r][3])), ck3);
            unsigned long long p0 = ((unsigned long long)__float_as_uint(d0) << 32) | (unsigned)(c0);
            unsigned long long p1 = ((unsigned long long)__float_as_uint(d1) << 32) | (unsigned)(c0 + 256);
            unsigned long long p2 = ((unsigned long long)__float_as_uint(d2) << 32) | (unsigned)(c0 + 512);
            unsigned long long p3 = ((unsigned long long)__float_as_uint(d3) << 32) | (unsigned)(c0 + 768);
            unsigned long long pa = p0 < p1 ? p0 : p1;
            unsigned long long pb = p2 < p3 ? p2 : p3;
            unsigned long long pm = pa < pb ? pa : pb;
            for (int msk = 32; msk >= 1; msk >>= 1) {
                unsigned long long qv = __shfl_xor(pm, msk);
                pm = qv < pm ? qv : pm;
            }
            if ((tid & 63) == 0) atomicMin(&rescored[srow[r]], pm);
        }
    }
}

// ---------------- writeback z_q_st + loss partials + fused index fixup (r9-verified) ----------------
__global__ __launch_bounds__(256) void writeback_kernel(
        const float* __restrict__ z, const float* __restrict__ emb,
        const unsigned long long* __restrict__ rescored,
        float* __restrict__ out_idx, float* __restrict__ out0,
        double* __restrict__ partials) {
    const int tid = threadIdx.x;
    const int base = blockIdx.x * 32;
    double acc = 0.0;
    for (int g = 0; g < 8; ++g) {
        int row = base + g * 4 + (tid >> 6);
        int d4 = tid & 63;
        unsigned long long rv = rescored[row];
        int idx;
        if (rv != ~0ull) {
            idx = (int)(unsigned)(rv & 0xffffffffull);
            if (d4 == 0) out_idx[row] = (float)idx;
        } else {
            idx = (int)out_idx[row];
        }
        float4 q4 = *(const float4*)&emb[(size_t)idx * D_DIM + d4 * 4];
        float4 z4 = *(const float4*)&z[(size_t)row * D_DIM + d4 * 4];
        float4 o;
        float dx;
        dx = q4.x - z4.x; o.x = z4.x + dx; acc += (double)dx * dx;
        dx = q4.y - z4.y; o.y = z4.y + dx; acc += (double)dx * dx;
        dx = q4.z - z4.z; o.z = z4.z + dx; acc += (double)dx * dx;
        dx = q4.w - z4.w; o.w = z4.w + dx; acc += (double)dx * dx;
        *(float4*)&out0[(size_t)row * D_DIM + d4 * 4] = o;
    }
    for (int m = 32; m >= 1; m >>= 1) acc += __shfl_xor(acc, m);
    __shared__ double sd[4];
    if ((tid & 63) == 0) sd[tid >> 6] = acc;
    __syncthreads();
    if (tid == 0) partials[blockIdx.x] = (sd[0] + sd[1]) + (sd[2] + sd[3]);
}

__global__ void finalize_kernel(const double* __restrict__ partials, float* __restrict__ out_loss) {
    __shared__ double sd[256];
    const int tid = threadIdx.x;
    double a = 0.0;
    for (int i = tid; i < 2048; i += 256) a += partials[i];
    sd[tid] = a;
    __syncthreads();
    for (int s = 128; s > 0; s >>= 1) {
        if (tid < s) sd[tid] += sd[tid + s];
        __syncthreads();
    }
    if (tid == 0) {
        double m = sd[0] / 16777216.0;
        out_loss[0] = (float)(m + 0.25 * m);
    }
}

extern "C" void kernel_launch(void* const* d_in, const int* in_sizes, int n_in,
                              void* d_out, int out_size, void* d_ws, size_t ws_size,
                              hipStream_t stream) {
    const float* z = (const float*)d_in[0];
    const float* emb = (const float*)d_in[1];
    float* out0 = (float*)d_out;
    float* out_loss = out0 + (size_t)N_ROWS * D_DIM;
    float* out_idx = out_loss + 1;

    char* ws = (char*)d_ws;
    float* cvec = (float*)(ws + 262144);
    unsigned short* emb_perm = (unsigned short*)(ws + 278528);
    int* cnts = (int*)(ws + 2375680);
    int* fulllist = (int*)(ws + 2375936);
    unsigned long long* duellist = (unsigned long long*)(ws + 2408704);
    unsigned long long* rescored = (unsigned long long*)(ws + 2605312);
    double* partials = (double*)(ws + 3129600);

    cvt_emb_kernel<<<576, 256, 0, stream>>>(emb, emb_perm, cvec, cnts, rescored);
    phaseB_kernel<<<1024, 256, 0, stream>>>(z, emb_perm, cvec, out_idx, cnts, fulllist, duellist);
    rescore_kernel<<<256, 256, 0, stream>>>(z, emb, cvec, cnts, fulllist, rescored);
    duel_kernel<<<64, 256, 0, stream>>>(z, emb, cvec, cnts, duellist, rescored);
    writeback_kernel<<<N_ROWS / 32, 256, 0, stream>>>(z, emb, rescored, out_idx, out0, partials);
    finalize_kernel<<<1, 256, 0, stream>>>(partials, out_loss);
}

// Round 19
// 286.679 us; speedup vs baseline: 1.1727x; 1.1727x over previous
//
#include <hip/hip_runtime.h>

#define N_ROWS 65536
#define K_CODES 4096
#define D_DIM 256
#define MARGIN_BF 6.0e-5f
#define CAP_DUEL 24576
#define CAP_FULL 8192

typedef __attribute__((ext_vector_type(8))) _Float16 f16x8;
typedef __attribute__((ext_vector_type(4))) float f32x4;

typedef __attribute__((address_space(1))) unsigned int g_u32;
typedef __attribute__((address_space(3))) unsigned int l_u32;
// async global->LDS, 16B per lane; LDS dest = wave-uniform base + lane*16
#define GLOAD16(gp, lp) __builtin_amdgcn_global_load_lds((g_u32*)(gp), (l_u32*)(lp), 16, 0, 0)

// ---------------- ws layout ----------------
// [262144]   float  cvec[4096]           16 KB
// [278528]   ushort emb_perm[4096*256]    2 MB   (f16 x4096, pair-major stream-linear)
// [2375680]  int    cnts[2]  (0=duel, 1=full)
// [2375936]  int    fulllist[8192]       32 KB
// [2408704]  u64    duellist[24576]     192 KB
// [2605312]  u64    rescored[65536]     512 KB
// [3129600]  double partials[2048]       16 KB
// z_perm (32 MB, f16 fragment-linear) lives in d_out as scratch;
// writeback_kernel fully overwrites d_out afterwards (deterministic each replay).

union f16u { _Float16 h; unsigned short u; };

static __device__ __forceinline__ unsigned int pack2(float a, float b) {
    f16u x, y; x.h = (_Float16)a; y.h = (_Float16)b;
    return (unsigned)x.u | ((unsigned)y.u << 16);
}

// ---------------- r2-verified norm chain (verbatim body, block-offset) ----------------
static __device__ __forceinline__ void norm_body(const float* __restrict__ src,
                                                 float* __restrict__ dst, int bi, int tid) {
    int row = bi * 64 + (tid >> 2);
    int q = tid & 3;
    const float* p = src + (size_t)row * D_DIM;
    double acc = 0.0;
#pragma unroll 4
    for (int it = 0; it < 16; ++it) {
        float4 v = *(const float4*)&p[(q + 4 * it) * 4];
        float a = v.x * v.x, b = v.y * v.y, c = v.z * v.z, d = v.w * v.w;
        acc += (double)a; acc += (double)b; acc += (double)c; acc += (double)d;
    }
    acc += __shfl_xor(acc, 1);
    acc += __shfl_xor(acc, 2);
    if (q == 0) dst[row] = (float)acc;
}

// ---------------- emb -> f16(x4096) pair-major + emb-norm + cnt/rescored clear (r17) ----------------
// frag f = (h*512 + step*8 + d8)*2 + cf ; lane part holds
// emb[h*2048 + step*32 + cf*16 + (lane&15)][d8*32 + (lane>>4)*8 + 0..7] * 4096
__global__ __launch_bounds__(256) void cvt_emb_kernel(const float* __restrict__ emb,
                                                      unsigned short* __restrict__ emb_perm,
                                                      float* __restrict__ cvec,
                                                      int* __restrict__ cnts,
                                                      unsigned long long* __restrict__ rescored) {
    if (blockIdx.x >= 512) {
        if (blockIdx.x == 512 && threadIdx.x < 2) cnts[threadIdx.x] = 0;
        norm_body(emb, cvec, blockIdx.x - 512, threadIdx.x);
        return;
    }
    if (blockIdx.x < 256) rescored[blockIdx.x * 256 + threadIdx.x] = ~0ull;
    int gid = blockIdx.x * 256 + threadIdx.x;     // 131072 16B units
    int lane = gid & 63;
    int f = gid >> 6;
    int cf = f & 1;
    int d8 = (f >> 1) & 7;
    int step = (f >> 4) & 63;
    int h = f >> 10;
    int code = h * 2048 + step * 32 + cf * 16 + (lane & 15);
    int d0 = d8 * 32 + (lane >> 4) * 8;
    const float* p = emb + (size_t)code * D_DIM + d0;
    float4 v0 = *(const float4*)p;
    float4 v1 = *(const float4*)(p + 4);
    uint4 o;
    o.x = pack2(v0.x * 4096.0f, v0.y * 4096.0f);
    o.y = pack2(v0.z * 4096.0f, v0.w * 4096.0f);
    o.z = pack2(v1.x * 4096.0f, v1.y * 4096.0f);
    o.w = pack2(v1.z * 4096.0f, v1.w * 4096.0f);
    *(uint4*)((char*)emb_perm + (size_t)gid * 16) = o;
}

// ---------------- z -> f16 fragment-linear (slim: pure permute, r11-verified layout) ----------------
// ft = rg*2048 + (d8*4 + rf)*64 + lane ; holds z[rg*64 + rf*16 + (lane&15)][d8*32 + (lane>>4)*8 + 0..7]
__global__ __launch_bounds__(256) void cvt_z_kernel(const float* __restrict__ z,
                                                    unsigned short* __restrict__ z_perm) {
    int ft = blockIdx.x * 256 + threadIdx.x;      // 2097152 frag-lanes
    int lane = ft & 63;
    int rf = (ft >> 6) & 3;
    int d8 = (ft >> 8) & 7;
    int rg = ft >> 11;
    int row = rg * 64 + rf * 16 + (lane & 15);
    int d0 = d8 * 32 + (lane >> 4) * 8;
    const float* p = z + (size_t)row * D_DIM + d0;
    float4 v0 = *(const float4*)p;
    float4 v1 = *(const float4*)(p + 4);
    uint4 o;
    o.x = pack2(v0.x, v0.y);
    o.y = pack2(v0.z, v0.w);
    o.z = pack2(v1.x, v1.y);
    o.w = pack2(v1.z, v1.w);
    *(uint4*)((char*)z_perm + (size_t)ft * 16) = o;
}

// ---------------- phase B: r16-verified twin-wave LDS ring + index-packed top-3 ----------------
// Block = 4 waves = 2 row-groups (pp: 64 rows, A from z_perm in AGPRs) x 2 code-halves (h).
// Shared 8-slot ring per h; counted vmcnt(5) + raw s_barrier (T4 counted-wait pattern).
__global__ __launch_bounds__(256, 2) void phaseB_kernel(
        const unsigned short* __restrict__ z_perm, const unsigned short* __restrict__ emb_perm,
        const float* __restrict__ cvec, float* __restrict__ out_idx,
        int* __restrict__ cnts, int* __restrict__ fulllist,
        unsigned long long* __restrict__ duellist) {
    __shared__ float cv[4096];                    // 16 KB cvec table; merge scratch after loop
    __shared__ unsigned short ring[2][8][1024];   // 32 KB: [h][slot][2KB pair]

    const int tid = threadIdx.x;
    const int lane = tid & 63;
    const int w = tid >> 6;
    const int pp = w >> 1;         // row group (also: which cf half this wave stages)
    const int h = w & 1;           // code half
    const int l15 = lane & 15, l4 = lane >> 4;
    const int rb = blockIdx.x;     // 512 blocks x 128 rows

    // ---- cvec -> LDS ----
#pragma unroll
    for (int i = 0; i < 4; ++i) {
        int idx = i * 1024 + tid * 4;
        *(float4*)&cv[idx] = *(const float4*)&cvec[idx];
    }

    // ---- A (64 rows) into registers (AGPR-eligible): 32 frags from z_perm ----
    f16x8 A[8][4];
    {
        const char* zsrc = (const char*)z_perm + (size_t)(rb * 2 + pp) * 32768 + lane * 16;
#pragma unroll
        for (int d8 = 0; d8 < 8; ++d8)
#pragma unroll
            for (int rf = 0; rf < 4; ++rf)
                A[d8][rf] = *(const f16x8*)(zsrc + (d8 * 4 + rf) * 1024);
    }
    __syncthreads();               // cv ready + vmcnt(0) drain: A retired, clean VM FIFO

    // ---- B ring setup: pair q at bsrc + q*2048 (this wave's cf=pp frag) ----
    const char* bsrc = (const char*)emb_perm + (size_t)h * 1048576 + pp * 1024 + lane * 16;
    char* ldst = (char*)&ring[h][0][0] + pp * 1024;        // uniform LDS dest base
    const char* lrd = (const char*)&ring[h][0][0] + lane * 16;

    // prologue: stage pairs 0..5 (depth 6)
#pragma unroll
    for (int q = 0; q < 6; ++q)
        GLOAD16(bsrc + q * 2048, ldst + q * 2048);
    asm volatile("s_waitcnt vmcnt(5)" ::: "memory");       // my pair-0 half landed
    __builtin_amdgcn_s_barrier();                          // partner's half landed too
    __builtin_amdgcn_sched_barrier(0);

    f16x8 B0a = *(const f16x8*)(lrd);                      // pair 0, cf0
    f16x8 B0b = *(const f16x8*)(lrd + 1024);               // pair 0, cf1
    f16x8 B1a, B1b;

    float m1[16], m2[16], m3[16];  // index-packed distances
#pragma unroll
    for (int t = 0; t < 16; ++t) { m1[t] = 3.4e38f; m2[t] = 3.4e38f; m3[t] = 3.4e38f; }

    f32x4 acc[4][2];

    for (int step = 0; step < 64; ++step) {
        const int kb = h * 2048 + step * 32;
        float ck0 = cv[kb + l15];
        float ck1 = cv[kb + 16 + l15];
#pragma unroll
        for (int rf = 0; rf < 4; ++rf) {
            acc[rf][0] = (f32x4){0.f, 0.f, 0.f, 0.f};
            acc[rf][1] = (f32x4){0.f, 0.f, 0.f, 0.f};
        }
#pragma unroll
        for (int d8 = 0; d8 < 8; ++d8) {
            // k = step*8 + d8. Stage pair k+6 into slot (d8+6)&7 (tail wraps to
            // pairs 0..5: re-stages dead slots with valid addrs, keeps counts uniform).
            {
                const char* g = bsrc + (size_t)(step * 8 + d8 + 6) * 2048
                                - ((step == 63 && d8 >= 2) ? 1048576 : 0);
                GLOAD16(g, ldst + ((d8 + 6) & 7) * 2048);
            }
            asm volatile("s_waitcnt vmcnt(5)" ::: "memory");   // pair k+1 (mine) landed
            __builtin_amdgcn_s_barrier();                      // partner's half landed
            __builtin_amdgcn_sched_barrier(0);
            // ds_read pair k+1 into reg slot (d8+1)&1 (lgkm hides across next iter)
            {
                const char* rp = lrd + ((d8 + 1) & 7) * 2048;
                if ((d8 + 1) & 1) { B1a = *(const f16x8*)rp; B1b = *(const f16x8*)(rp + 1024); }
                else              { B0a = *(const f16x8*)rp; B0b = *(const f16x8*)(rp + 1024); }
            }
            f16x8 b0 = (d8 & 1) ? B1a : B0a;   // pair k from slot d8&1
            f16x8 b1 = (d8 & 1) ? B1b : B0b;
#pragma unroll
            for (int rf = 0; rf < 4; ++rf) {
                acc[rf][0] = __builtin_amdgcn_mfma_f32_16x16x32_f16(A[d8][rf], b0, acc[rf][0], 0, 0, 0);
                acc[rf][1] = __builtin_amdgcn_mfma_f32_16x16x32_f16(A[d8][rf], b1, acc[rf][1], 0, 0, 0);
            }
        }

        // ---- epilogue: index-packed running top-3 over this step's 32 codes (r15-verified) ----
#pragma unroll
        for (int cf = 0; cf < 2; ++cf) {
            const float ck = cf ? ck1 : ck0;
            const unsigned cg = (unsigned)(kb + cf * 16 + l15);
#pragma unroll
            for (int rf = 0; rf < 4; ++rf)
#pragma unroll
                for (int j = 0; j < 4; ++j) {
                    // acc = z.(4096 e); -2*dot = acc * -2^-11 (exact scale)
                    float d = fmaf(-4.8828125e-4f, acc[rf][cf][j], ck);
                    float dp = __uint_as_float((__float_as_uint(d) & 0xfffff000u) | cg);
                    const int t = rf * 4 + j;
                    m3[t] = __builtin_amdgcn_fmed3f(dp, m2[t], m3[t]);
                    m2[t] = __builtin_amdgcn_fmed3f(dp, m1[t], m2[t]);
                    m1[t] = fminf(m1[t], dp);
                }
        }
    }

    // ---- per-wave merge across the 16 column-lanes (sorted-triple merge, r15-verified) ----
    __syncthreads();               // cv dead; reuse as merge scratch
    float* m1s = cv;               // [4][64]
    float* m2s = cv + 256;
    float* m3s = cv + 512;
#pragma unroll
    for (int t = 0; t < 16; ++t) {
        float a1 = m1[t], a2 = m2[t], a3 = m3[t];
        for (int msk = 8; msk >= 1; msk >>= 1) {
            float b1 = __shfl_xor(a1, msk);
            float b2 = __shfl_xor(a2, msk);
            float b3 = __shfl_xor(a3, msk);
            bool bw = b1 < a1;
            float w1 = bw ? b1 : a1, w2 = bw ? b2 : a2, w3 = bw ? b3 : a3;
            float l1 = bw ? a1 : b1, l2 = bw ? a2 : b2;
            bool t2 = l1 < w2;
            a1 = w1;
            a2 = t2 ? l1 : w2;
            a3 = t2 ? fminf(w2, l2) : fminf(w3, l1);
        }
        if (l15 == 0) {
            int rloc = (t >> 2) * 16 + l4 * 4 + (t & 3);
            m1s[w * 64 + rloc] = a1;
            m2s[w * 64 + rloc] = a2;
            m3s[w * 64 + rloc] = a3;
        }
    }
    __syncthreads();

    // ---- cross-wave merge (two code halves) + flag taxonomy (r15-verified) ----
    if (tid < 128) {
        int pg = tid >> 6, r = tid & 63;
        int wA = pg * 2, wB = pg * 2 + 1;
        float a1 = m1s[wA * 64 + r], a2 = m2s[wA * 64 + r], a3 = m3s[wA * 64 + r];
        float b1 = m1s[wB * 64 + r], b2 = m2s[wB * 64 + r], b3 = m3s[wB * 64 + r];
        bool bw = b1 < a1;
        float w1 = bw ? b1 : a1, w2 = bw ? b2 : a2, w3 = bw ? b3 : a3;
        float l1 = bw ? a1 : b1, l2 = bw ? a2 : b2;
        bool t2 = l1 < w2;
        float f1 = w1;
        float f2 = t2 ? l1 : w2;
        float f3 = t2 ? fminf(w2, l2) : fminf(w3, l1);

        int i1 = (int)(__float_as_uint(f1) & 0xfffu);
        int i2 = (int)(__float_as_uint(f2) & 0xfffu);
        int rowg = rb * 128 + pg * 64 + r;
        out_idx[rowg] = (float)i1;
        if (f3 - f1 < MARGIN_BF) {                 // 3+ candidates: full exact rescan
            int pz = atomicAdd(&cnts[1], 1);
            if (pz < CAP_FULL) fulllist[pz] = rowg;
        } else if (f2 - f1 < MARGIN_BF) {          // exactly 2 candidates: exact duel
            int pz = atomicAdd(&cnts[0], 1);
            if (pz < CAP_DUEL) {
                duellist[pz] = ((unsigned long long)(unsigned)rowg << 32) |
                               ((unsigned)i1 << 16) | (unsigned)i2;
            } else {
                int pf = atomicAdd(&cnts[1], 1);
                if (pf < CAP_FULL) fulllist[pf] = rowg;
            }
        }
    }
}

// ---------------- exact duel: f32 chain (r2) on {i1,i2}; rownorm on the fly (r17-verified) ----------------
__global__ __launch_bounds__(256) void duel_kernel(
        const float* __restrict__ z, const float* __restrict__ emb,
        const float* __restrict__ cvec,
        const int* __restrict__ cnts, const unsigned long long* __restrict__ duellist,
        unsigned long long* __restrict__ rescored) {
    int n = cnts[0];
    if (n > CAP_DUEL) n = CAP_DUEL;
    for (int i = blockIdx.x * 256 + threadIdx.x; i < n; i += 64 * 256) {
        unsigned long long e = duellist[i];
        int row = (int)(e >> 32);
        int c1 = (int)((e >> 16) & 0xfffu);
        int c2 = (int)(e & 0xfffu);
        const float* zp = z + (size_t)row * D_DIM;
        const float* p1 = emb + (size_t)c1 * D_DIM;
        const float* p2 = emb + (size_t)c2 * D_DIM;
        float a1 = 0.f, a2 = 0.f;
        double n0 = 0.0, n1 = 0.0, n2 = 0.0, n3 = 0.0;  // q-partials: r2-chain order
#pragma unroll 8
        for (int d4 = 0; d4 < 64; ++d4) {          // d ascending, xyzw: r2 chain
            float4 zf = *(const float4*)&zp[d4 * 4];
            float4 e1 = *(const float4*)&p1[d4 * 4];
            float4 e2 = *(const float4*)&p2[d4 * 4];
            a1 = fmaf(zf.x, e1.x, a1); a1 = fmaf(zf.y, e1.y, a1);
            a1 = fmaf(zf.z, e1.z, a1); a1 = fmaf(zf.w, e1.w, a1);
            a2 = fmaf(zf.x, e2.x, a2); a2 = fmaf(zf.y, e2.y, a2);
            a2 = fmaf(zf.z, e2.z, a2); a2 = fmaf(zf.w, e2.w, a2);
            float sx = zf.x * zf.x, sy = zf.y * zf.y, sz = zf.z * zf.z, sw = zf.w * zf.w;
            switch (d4 & 3) {                      // q = d4&3, it ascending: bit-exact r2 chain
                case 0: n0 += (double)sx; n0 += (double)sy; n0 += (double)sz; n0 += (double)sw; break;
                case 1: n1 += (double)sx; n1 += (double)sy; n1 += (double)sz; n1 += (double)sw; break;
                case 2: n2 += (double)sx; n2 += (double)sy; n2 += (double)sz; n2 += (double)sw; break;
                default: n3 += (double)sx; n3 += (double)sy; n3 += (double)sz; n3 += (double)sw; break;
            }
        }
        float rn = (float)((n0 + n1) + (n2 + n3));
        float d1 = __fadd_rn(__fsub_rn(rn, __fmul_rn(2.0f, a1)), cvec[c1]);
        float d2 = __fadd_rn(__fsub_rn(rn, __fmul_rn(2.0f, a2)), cvec[c2]);
        unsigned long long p1v = ((unsigned long long)__float_as_uint(d1) << 32) | (unsigned)c1;
        unsigned long long p2v = ((unsigned long long)__float_as_uint(d2) << 32) | (unsigned)c2;
        rescored[row] = p1v < p2v ? p1v : p2v;     // dist>0 -> f32 bits monotone
    }
}

// ---------------- full exact rescan (r2-chain); rownorm from staged zs (r17-verified) ----------------
__global__ __launch_bounds__(256) void rescore_kernel(
        const float* __restrict__ z, const float* __restrict__ emb,
        const float* __restrict__ cvec,
        const int* __restrict__ cnts, const int* __restrict__ fulllist,
        unsigned long long* __restrict__ rescored) {
    __shared__ float zs[16][256];
    __shared__ float sa[16];
    __shared__ int srow[16];
    const int tid = threadIdx.x;
    int cnt = cnts[1];
    if (cnt > CAP_FULL) cnt = CAP_FULL;
    const int nu = ((cnt + 15) >> 4) << 2;   // ceil(cnt/16) row-groups x 4 code-splits
    for (int uu = blockIdx.x; uu < nu; uu += gridDim.x) {
        int rg = uu >> 2, ks = uu & 3;
        __syncthreads();
        if (tid < 16) {
            int fi = rg * 16 + tid;
            srow[tid] = fulllist[fi < cnt ? fi : 0];
        }
        __syncthreads();
#pragma unroll
        for (int i = 0; i < 4; ++i) {
            int u = i * 256 + tid;
            int r = u >> 6, d4 = u & 63;
            *(float4*)&zs[r][d4 * 4] = *(const float4*)&z[(size_t)srow[r] * D_DIM + d4 * 4];
        }
        __syncthreads();
        if (tid < 64) {                        // sa via r2 shfl-chain on staged zs
            int r = tid >> 2, q = tid & 3;
            double acc = 0.0;
#pragma unroll 4
            for (int it = 0; it < 16; ++it) {
                float4 v = *(const float4*)&zs[r][(q + 4 * it) * 4];
                float a = v.x * v.x, b = v.y * v.y, c = v.z * v.z, d = v.w * v.w;
                acc += (double)a; acc += (double)b; acc += (double)c; acc += (double)d;
            }
            acc += __shfl_xor(acc, 1);
            acc += __shfl_xor(acc, 2);
            if (q == 0) sa[r] = (float)acc;
        }
        __syncthreads();

        const int c0 = ks * 1024 + tid;
        float acc[16][4];
#pragma unroll
        for (int r = 0; r < 16; ++r)
#pragma unroll
            for (int j = 0; j < 4; ++j) acc[r][j] = 0.f;

        for (int ch = 0; ch < 8; ++ch) {
#pragma unroll
            for (int q = 0; q < 8; ++q) {
                float4 e0 = *(const float4*)&emb[(size_t)(c0      ) * D_DIM + ch * 32 + q * 4];
                float4 e1 = *(const float4*)&emb[(size_t)(c0 + 256) * D_DIM + ch * 32 + q * 4];
                float4 e2 = *(const float4*)&emb[(size_t)(c0 + 512) * D_DIM + ch * 32 + q * 4];
                float4 e3 = *(const float4*)&emb[(size_t)(c0 + 768) * D_DIM + ch * 32 + q * 4];
#pragma unroll
                for (int r = 0; r < 16; ++r) {
                    float4 zf = *(const float4*)&zs[r][ch * 32 + q * 4];
                    acc[r][0] = fmaf(zf.x, e0.x, acc[r][0]);
                    acc[r][0] = fmaf(zf.y, e0.y, acc[r][0]);
                    acc[r][0] = fmaf(zf.z, e0.z, acc[r][0]);
                    acc[r][0] = fmaf(zf.w, e0.w, acc[r][0]);
                    acc[r][1] = fmaf(zf.x, e1.x, acc[r][1]);
                    acc[r][1] = fmaf(zf.y, e1.y, acc[r][1]);
                    acc[r][1] = fmaf(zf.z, e1.z, acc[r][1]);
                    acc[r][1] = fmaf(zf.w, e1.w, acc[r][1]);
                    acc[r][2] = fmaf(zf.x, e2.x, acc[r][2]);
                    acc[r][2] = fmaf(zf.y, e2.y, acc[r][2]);
                    acc[r][2] = fmaf(zf.z, e2.z, acc[r][2]);
                    acc[r][2] = fmaf(zf.w, e2.w, acc[r][2]);
                    acc[r][3] = fmaf(zf.x, e3.x, acc[r][3]);
                    acc[r][3] = fmaf(zf.y, e3.y, acc[r][3]);
                    acc[r][3] = fmaf(zf.z, e3.z, acc[r][3]);
                    acc[r][3] = fmaf(zf.w, e3.w, acc[r][3]);
                }
            }
        }
        const float ck0 = cvec[c0], ck1 = cvec[c0 + 256];
        const float ck2 = cvec[c0 + 512], ck3 = cvec[c0 + 768];
#pragma unroll
        for (int r = 0; r < 16; ++r) {
            float d0 = __fadd_rn(__fsub_rn(sa[r], __fmul_rn(2.0f, acc[r][0])), ck0);
            float d1 = __fadd_rn(__fsub_rn(sa[r], __fmul_rn(2.0f, acc[r][1])), ck1);
            float d2 = __fadd_rn(__fsub_rn(sa[r], __fmul_rn(2.0f, acc[r][2])), ck2);
            float d3 = __fadd_rn(__fsub_rn(sa[r], __fmul_rn(2.0f, acc[r][3])), ck3);
            unsigned long long p0 = ((unsigned long long)__float_as_uint(d0) << 32) | (unsigned)(c0);
            unsigned long long p1 = ((unsigned long long)__float_as_uint(d1) << 32) | (unsigned)(c0 + 256);
            unsigned long long p2 = ((unsigned long long)__float_as_uint(d2) << 32) | (unsigned)(c0 + 512);
            unsigned long long p3 = ((unsigned long long)__float_as_uint(d3) << 32) | (unsigned)(c0 + 768);
            unsigned long long pa = p0 < p1 ? p0 : p1;
            unsigned long long pb = p2 < p3 ? p2 : p3;
            unsigned long long pm = pa < pb ? pa : pb;
            for (int msk = 32; msk >= 1; msk >>= 1) {
                unsigned long long qv = __shfl_xor(pm, msk);
                pm = qv < pm ? qv : pm;
            }
            if ((tid & 63) == 0) atomicMin(&rescored[srow[r]], pm);
        }
    }
}

// ---------------- writeback z_q_st + loss partials + fused index fixup (r9-verified) ----------------
__global__ __launch_bounds__(256) void writeback_kernel(
        const float* __restrict__ z, const float* __restrict__ emb,
        const unsigned long long* __restrict__ rescored,
        float* __restrict__ out_idx, float* __restrict__ out0,
        double* __restrict__ partials) {
    const int tid = threadIdx.x;
    const int base = blockIdx.x * 32;
    double acc = 0.0;
    for (int g = 0; g < 8; ++g) {
        int row = base + g * 4 + (tid >> 6);
        int d4 = tid & 63;
        unsigned long long rv = rescored[row];
        int idx;
        if (rv != ~0ull) {
            idx = (int)(unsigned)(rv & 0xffffffffull);
            if (d4 == 0) out_idx[row] = (float)idx;
        } else {
            idx = (int)out_idx[row];
        }
        float4 q4 = *(const float4*)&emb[(size_t)idx * D_DIM + d4 * 4];
        float4 z4 = *(const float4*)&z[(size_t)row * D_DIM + d4 * 4];
        float4 o;
        float dx;
        dx = q4.x - z4.x; o.x = z4.x + dx; acc += (double)dx * dx;
        dx = q4.y - z4.y; o.y = z4.y + dx; acc += (double)dx * dx;
        dx = q4.z - z4.z; o.z = z4.z + dx; acc += (double)dx * dx;
        dx = q4.w - z4.w; o.w = z4.w + dx; acc += (double)dx * dx;
        *(float4*)&out0[(size_t)row * D_DIM + d4 * 4] = o;
    }
    for (int m = 32; m >= 1; m >>= 1) acc += __shfl_xor(acc, m);
    __shared__ double sd[4];
    if ((tid & 63) == 0) sd[tid >> 6] = acc;
    __syncthreads();
    if (tid == 0) partials[blockIdx.x] = (sd[0] + sd[1]) + (sd[2] + sd[3]);
}

__global__ void finalize_kernel(const double* __restrict__ partials, float* __restrict__ out_loss) {
    __shared__ double sd[256];
    const int tid = threadIdx.x;
    double a = 0.0;
    for (int i = tid; i < 2048; i += 256) a += partials[i];
    sd[tid] = a;
    __syncthreads();
    for (int s = 128; s > 0; s >>= 1) {
        if (tid < s) sd[tid] += sd[tid + s];
        __syncthreads();
    }
    if (tid == 0) {
        double m = sd[0] / 16777216.0;
        out_loss[0] = (float)(m + 0.25 * m);
    }
}

extern "C" void kernel_launch(void* const* d_in, const int* in_sizes, int n_in,
                              void* d_out, int out_size, void* d_ws, size_t ws_size,
                              hipStream_t stream) {
    const float* z = (const float*)d_in[0];
    const float* emb = (const float*)d_in[1];
    float* out0 = (float*)d_out;
    float* out_loss = out0 + (size_t)N_ROWS * D_DIM;
    float* out_idx = out_loss + 1;

    char* ws = (char*)d_ws;
    float* cvec = (float*)(ws + 262144);
    unsigned short* emb_perm = (unsigned short*)(ws + 278528);
    int* cnts = (int*)(ws + 2375680);
    int* fulllist = (int*)(ws + 2375936);
    unsigned long long* duellist = (unsigned long long*)(ws + 2408704);
    unsigned long long* rescored = (unsigned long long*)(ws + 2605312);
    double* partials = (double*)(ws + 3129600);

    // 32 MB z_perm scratch inside d_out (fully overwritten by writeback_kernel)
    unsigned short* z_perm = (unsigned short*)d_out;

    cvt_emb_kernel<<<576, 256, 0, stream>>>(emb, emb_perm, cvec, cnts, rescored);
    cvt_z_kernel<<<8192, 256, 0, stream>>>(z, z_perm);
    phaseB_kernel<<<512, 256, 0, stream>>>(z_perm, emb_perm, cvec, out_idx, cnts, fulllist, duellist);
    rescore_kernel<<<256, 256, 0, stream>>>(z, emb, cvec, cnts, fulllist, rescored);
    duel_kernel<<<64, 256, 0, stream>>>(z, emb, cvec, cnts, duellist, rescored);
    writeback_kernel<<<N_ROWS / 32, 256, 0, stream>>>(z, emb, rescored, out_idx, out0, partials);
    finalize_kernel<<<1, 256, 0, stream>>>(partials, out_loss);
}

// Round 20
// 279.064 us; speedup vs baseline: 1.2047x; 1.0273x over previous
//
#include <hip/hip_runtime.h>

#define N_ROWS 65536
#define K_CODES 4096
#define D_DIM 256
#define MARGIN_BF 6.0e-5f
#define CAP_DUEL 24576
#define CAP_FULL 8192

typedef __attribute__((ext_vector_type(8))) _Float16 f16x8;
typedef __attribute__((ext_vector_type(4))) float f32x4;

typedef __attribute__((address_space(1))) unsigned int g_u32;
typedef __attribute__((address_space(3))) unsigned int l_u32;
// async global->LDS, 16B per lane; LDS dest = wave-uniform base + lane*16
#define GLOAD16(gp, lp) __builtin_amdgcn_global_load_lds((g_u32*)(gp), (l_u32*)(lp), 16, 0, 0)

// ---------------- ws layout ----------------
// [262144]   float  cvec[4096]           16 KB
// [278528]   ushort emb_perm[4096*256]    2 MB   (f16 x4096, pair-major stream-linear)
// [2375680]  int    cnts[2]  (0=duel, 1=full)
// [2375936]  int    fulllist[8192]       32 KB
// [2408704]  u64    duellist[24576]     192 KB
// [2605312]  u64    rescored[65536]     512 KB
// [3129600]  double partials[4096]       32 KB
// z_perm (32 MB, f16 fragment-linear) lives in d_out as scratch;
// writeback_kernel fully overwrites d_out afterwards (deterministic each replay).

union f16u { _Float16 h; unsigned short u; };

static __device__ __forceinline__ unsigned int pack2(float a, float b) {
    f16u x, y; x.h = (_Float16)a; y.h = (_Float16)b;
    return (unsigned)x.u | ((unsigned)y.u << 16);
}

// ---------------- r2-verified norm chain (verbatim body, block-offset) ----------------
static __device__ __forceinline__ void norm_body(const float* __restrict__ src,
                                                 float* __restrict__ dst, int bi, int tid) {
    int row = bi * 64 + (tid >> 2);
    int q = tid & 3;
    const float* p = src + (size_t)row * D_DIM;
    double acc = 0.0;
#pragma unroll 4
    for (int it = 0; it < 16; ++it) {
        float4 v = *(const float4*)&p[(q + 4 * it) * 4];
        float a = v.x * v.x, b = v.y * v.y, c = v.z * v.z, d = v.w * v.w;
        acc += (double)a; acc += (double)b; acc += (double)c; acc += (double)d;
    }
    acc += __shfl_xor(acc, 1);
    acc += __shfl_xor(acc, 2);
    if (q == 0) dst[row] = (float)acc;
}

// ---------------- fused prep: z-permute + emb-permute + emb-norm + clears ----------------
// blocks 0..8191:    z -> f16 fragment-linear (r11-verified layout); blocks 0..255 clear rescored
// blocks 8192..8703: emb -> f16(x4096) pair-major (r17-verified layout)
// blocks 8704..8767: emb norms (r2 chain); block 8704 clears cnts
__global__ __launch_bounds__(256) void cvt_all_kernel(const float* __restrict__ z,
                                                      const float* __restrict__ emb,
                                                      unsigned short* __restrict__ z_perm,
                                                      unsigned short* __restrict__ emb_perm,
                                                      float* __restrict__ cvec,
                                                      int* __restrict__ cnts,
                                                      unsigned long long* __restrict__ rescored) {
    const int b = blockIdx.x;
    const int tid = threadIdx.x;
    if (b < 8192) {
        if (b < 256) rescored[b * 256 + tid] = ~0ull;
        int ft = b * 256 + tid;                   // 2097152 frag-lanes
        int lane = ft & 63;
        int rf = (ft >> 6) & 3;
        int d8 = (ft >> 8) & 7;
        int rg = ft >> 11;
        int row = rg * 64 + rf * 16 + (lane & 15);
        int d0 = d8 * 32 + (lane >> 4) * 8;
        const float* p = z + (size_t)row * D_DIM + d0;
        float4 v0 = *(const float4*)p;
        float4 v1 = *(const float4*)(p + 4);
        uint4 o;
        o.x = pack2(v0.x, v0.y);
        o.y = pack2(v0.z, v0.w);
        o.z = pack2(v1.x, v1.y);
        o.w = pack2(v1.z, v1.w);
        *(uint4*)((char*)z_perm + (size_t)ft * 16) = o;
    } else if (b < 8704) {
        int gid = (b - 8192) * 256 + tid;         // 131072 16B units
        int lane = gid & 63;
        int f = gid >> 6;
        int cf = f & 1;
        int d8 = (f >> 1) & 7;
        int step = (f >> 4) & 63;
        int h = f >> 10;
        int code = h * 2048 + step * 32 + cf * 16 + (lane & 15);
        int d0 = d8 * 32 + (lane >> 4) * 8;
        const float* p = emb + (size_t)code * D_DIM + d0;
        float4 v0 = *(const float4*)p;
        float4 v1 = *(const float4*)(p + 4);
        uint4 o;
        o.x = pack2(v0.x * 4096.0f, v0.y * 4096.0f);
        o.y = pack2(v0.z * 4096.0f, v0.w * 4096.0f);
        o.z = pack2(v1.x * 4096.0f, v1.y * 4096.0f);
        o.w = pack2(v1.z * 4096.0f, v1.w * 4096.0f);
        *(uint4*)((char*)emb_perm + (size_t)gid * 16) = o;
    } else {
        if (b == 8704 && tid < 2) cnts[tid] = 0;
        norm_body(emb, cvec, b - 8704, tid);
    }
}

// ---------------- phase B: r16/r19-verified twin-wave LDS ring + index-packed top-3 ----------------
// Block = 4 waves = 2 row-groups (pp: 64 rows, A from z_perm in AGPRs) x 2 code-halves (h).
// Shared 8-slot ring per h; counted vmcnt(5) + raw s_barrier (T4 counted-wait pattern).
__global__ __launch_bounds__(256, 2) void phaseB_kernel(
        const unsigned short* __restrict__ z_perm, const unsigned short* __restrict__ emb_perm,
        const float* __restrict__ cvec, float* __restrict__ out_idx,
        int* __restrict__ cnts, int* __restrict__ fulllist,
        unsigned long long* __restrict__ duellist) {
    __shared__ float cv[4096];                    // 16 KB cvec table; merge scratch after loop
    __shared__ unsigned short ring[2][8][1024];   // 32 KB: [h][slot][2KB pair]

    const int tid = threadIdx.x;
    const int lane = tid & 63;
    const int w = tid >> 6;
    const int pp = w >> 1;         // row group (also: which cf half this wave stages)
    const int h = w & 1;           // code half
    const int l15 = lane & 15, l4 = lane >> 4;
    const int rb = blockIdx.x;     // 512 blocks x 128 rows

    // ---- cvec -> LDS ----
#pragma unroll
    for (int i = 0; i < 4; ++i) {
        int idx = i * 1024 + tid * 4;
        *(float4*)&cv[idx] = *(const float4*)&cvec[idx];
    }

    // ---- A (64 rows) into registers (AGPR-eligible): 32 frags from z_perm ----
    f16x8 A[8][4];
    {
        const char* zsrc = (const char*)z_perm + (size_t)(rb * 2 + pp) * 32768 + lane * 16;
#pragma unroll
        for (int d8 = 0; d8 < 8; ++d8)
#pragma unroll
            for (int rf = 0; rf < 4; ++rf)
                A[d8][rf] = *(const f16x8*)(zsrc + (d8 * 4 + rf) * 1024);
    }
    __syncthreads();               // cv ready + vmcnt(0) drain: A retired, clean VM FIFO

    // ---- B ring setup: pair q at bsrc + q*2048 (this wave's cf=pp frag) ----
    const char* bsrc = (const char*)emb_perm + (size_t)h * 1048576 + pp * 1024 + lane * 16;
    char* ldst = (char*)&ring[h][0][0] + pp * 1024;        // uniform LDS dest base
    const char* lrd = (const char*)&ring[h][0][0] + lane * 16;

    // prologue: stage pairs 0..5 (depth 6)
#pragma unroll
    for (int q = 0; q < 6; ++q)
        GLOAD16(bsrc + q * 2048, ldst + q * 2048);
    asm volatile("s_waitcnt vmcnt(5)" ::: "memory");       // my pair-0 half landed
    __builtin_amdgcn_s_barrier();                          // partner's half landed too
    __builtin_amdgcn_sched_barrier(0);

    f16x8 B0a = *(const f16x8*)(lrd);                      // pair 0, cf0
    f16x8 B0b = *(const f16x8*)(lrd + 1024);               // pair 0, cf1
    f16x8 B1a, B1b;

    float m1[16], m2[16], m3[16];  // index-packed distances
#pragma unroll
    for (int t = 0; t < 16; ++t) { m1[t] = 3.4e38f; m2[t] = 3.4e38f; m3[t] = 3.4e38f; }

    f32x4 acc[4][2];

    for (int step = 0; step < 64; ++step) {
        const int kb = h * 2048 + step * 32;
        float ck0 = cv[kb + l15];
        float ck1 = cv[kb + 16 + l15];
#pragma unroll
        for (int rf = 0; rf < 4; ++rf) {
            acc[rf][0] = (f32x4){0.f, 0.f, 0.f, 0.f};
            acc[rf][1] = (f32x4){0.f, 0.f, 0.f, 0.f};
        }
#pragma unroll
        for (int d8 = 0; d8 < 8; ++d8) {
            // k = step*8 + d8. Stage pair k+6 into slot (d8+6)&7 (tail wraps to
            // pairs 0..5: re-stages dead slots with valid addrs, keeps counts uniform).
            {
                const char* g = bsrc + (size_t)(step * 8 + d8 + 6) * 2048
                                - ((step == 63 && d8 >= 2) ? 1048576 : 0);
                GLOAD16(g, ldst + ((d8 + 6) & 7) * 2048);
            }
            asm volatile("s_waitcnt vmcnt(5)" ::: "memory");   // pair k+1 (mine) landed
            __builtin_amdgcn_s_barrier();                      // partner's half landed
            __builtin_amdgcn_sched_barrier(0);
            // ds_read pair k+1 into reg slot (d8+1)&1 (lgkm hides across next iter)
            {
                const char* rp = lrd + ((d8 + 1) & 7) * 2048;
                if ((d8 + 1) & 1) { B1a = *(const f16x8*)rp; B1b = *(const f16x8*)(rp + 1024); }
                else              { B0a = *(const f16x8*)rp; B0b = *(const f16x8*)(rp + 1024); }
            }
            f16x8 b0 = (d8 & 1) ? B1a : B0a;   // pair k from slot d8&1
            f16x8 b1 = (d8 & 1) ? B1b : B0b;
#pragma unroll
            for (int rf = 0; rf < 4; ++rf) {
                acc[rf][0] = __builtin_amdgcn_mfma_f32_16x16x32_f16(A[d8][rf], b0, acc[rf][0], 0, 0, 0);
                acc[rf][1] = __builtin_amdgcn_mfma_f32_16x16x32_f16(A[d8][rf], b1, acc[rf][1], 0, 0, 0);
            }
        }

        // ---- epilogue: index-packed running top-3 over this step's 32 codes (r15-verified) ----
#pragma unroll
        for (int cf = 0; cf < 2; ++cf) {
            const float ck = cf ? ck1 : ck0;
            const unsigned cg = (unsigned)(kb + cf * 16 + l15);
#pragma unroll
            for (int rf = 0; rf < 4; ++rf)
#pragma unroll
                for (int j = 0; j < 4; ++j) {
                    // acc = z.(4096 e); -2*dot = acc * -2^-11 (exact scale)
                    float d = fmaf(-4.8828125e-4f, acc[rf][cf][j], ck);
                    float dp = __uint_as_float((__float_as_uint(d) & 0xfffff000u) | cg);
                    const int t = rf * 4 + j;
                    m3[t] = __builtin_amdgcn_fmed3f(dp, m2[t], m3[t]);
                    m2[t] = __builtin_amdgcn_fmed3f(dp, m1[t], m2[t]);
                    m1[t] = fminf(m1[t], dp);
                }
        }
    }

    // ---- per-wave merge across the 16 column-lanes (sorted-triple merge, r15-verified) ----
    __syncthreads();               // cv dead; reuse as merge scratch
    float* m1s = cv;               // [4][64]
    float* m2s = cv + 256;
    float* m3s = cv + 512;
#pragma unroll
    for (int t = 0; t < 16; ++t) {
        float a1 = m1[t], a2 = m2[t], a3 = m3[t];
        for (int msk = 8; msk >= 1; msk >>= 1) {
            float b1 = __shfl_xor(a1, msk);
            float b2 = __shfl_xor(a2, msk);
            float b3 = __shfl_xor(a3, msk);
            bool bw = b1 < a1;
            float w1 = bw ? b1 : a1, w2 = bw ? b2 : a2, w3 = bw ? b3 : a3;
            float l1 = bw ? a1 : b1, l2 = bw ? a2 : b2;
            bool t2 = l1 < w2;
            a1 = w1;
            a2 = t2 ? l1 : w2;
            a3 = t2 ? fminf(w2, l2) : fminf(w3, l1);
        }
        if (l15 == 0) {
            int rloc = (t >> 2) * 16 + l4 * 4 + (t & 3);
            m1s[w * 64 + rloc] = a1;
            m2s[w * 64 + rloc] = a2;
            m3s[w * 64 + rloc] = a3;
        }
    }
    __syncthreads();

    // ---- cross-wave merge (two code halves) + flag taxonomy (r15-verified) ----
    if (tid < 128) {
        int pg = tid >> 6, r = tid & 63;
        int wA = pg * 2, wB = pg * 2 + 1;
        float a1 = m1s[wA * 64 + r], a2 = m2s[wA * 64 + r], a3 = m3s[wA * 64 + r];
        float b1 = m1s[wB * 64 + r], b2 = m2s[wB * 64 + r], b3 = m3s[wB * 64 + r];
        bool bw = b1 < a1;
        float w1 = bw ? b1 : a1, w2 = bw ? b2 : a2, w3 = bw ? b3 : a3;
        float l1 = bw ? a1 : b1, l2 = bw ? a2 : b2;
        bool t2 = l1 < w2;
        float f1 = w1;
        float f2 = t2 ? l1 : w2;
        float f3 = t2 ? fminf(w2, l2) : fminf(w3, l1);

        int i1 = (int)(__float_as_uint(f1) & 0xfffu);
        int i2 = (int)(__float_as_uint(f2) & 0xfffu);
        int rowg = rb * 128 + pg * 64 + r;
        out_idx[rowg] = (float)i1;
        if (f3 - f1 < MARGIN_BF) {                 // 3+ candidates: full exact rescan
            int pz = atomicAdd(&cnts[1], 1);
            if (pz < CAP_FULL) fulllist[pz] = rowg;
        } else if (f2 - f1 < MARGIN_BF) {          // exactly 2 candidates: exact duel
            int pz = atomicAdd(&cnts[0], 1);
            if (pz < CAP_DUEL) {
                duellist[pz] = ((unsigned long long)(unsigned)rowg << 32) |
                               ((unsigned)i1 << 16) | (unsigned)i2;
            } else {
                int pf = atomicAdd(&cnts[1], 1);
                if (pf < CAP_FULL) fulllist[pf] = rowg;
            }
        }
    }
}

// ---------------- fused refine: full rescan (blocks 0..255) + duels (blocks 256..319) ----------------
// Row sets are disjoint (if/else taxonomy), so plain-store duels and atomicMin rescans
// never touch the same rescored[] entry.
__global__ __launch_bounds__(256) void refine_kernel(
        const float* __restrict__ z, const float* __restrict__ emb,
        const float* __restrict__ cvec,
        const int* __restrict__ cnts, const int* __restrict__ fulllist,
        const unsigned long long* __restrict__ duellist,
        unsigned long long* __restrict__ rescored) {
    __shared__ float zs[16][256];
    __shared__ float sa[16];
    __shared__ int srow[16];
    const int tid = threadIdx.x;

    if (blockIdx.x >= 256) {
        // ---- duel path (r17-verified): f32 r2 chain on {i1,i2}, norm on the fly ----
        int n = cnts[0];
        if (n > CAP_DUEL) n = CAP_DUEL;
        for (int i = (blockIdx.x - 256) * 256 + tid; i < n; i += 64 * 256) {
            unsigned long long e = duellist[i];
            int row = (int)(e >> 32);
            int c1 = (int)((e >> 16) & 0xfffu);
            int c2 = (int)(e & 0xfffu);
            const float* zp = z + (size_t)row * D_DIM;
            const float* p1 = emb + (size_t)c1 * D_DIM;
            const float* p2 = emb + (size_t)c2 * D_DIM;
            float a1 = 0.f, a2 = 0.f;
            double n0 = 0.0, n1 = 0.0, n2 = 0.0, n3 = 0.0;
#pragma unroll 8
            for (int d4 = 0; d4 < 64; ++d4) {      // d ascending, xyzw: r2 chain
                float4 zf = *(const float4*)&zp[d4 * 4];
                float4 e1 = *(const float4*)&p1[d4 * 4];
                float4 e2 = *(const float4*)&p2[d4 * 4];
                a1 = fmaf(zf.x, e1.x, a1); a1 = fmaf(zf.y, e1.y, a1);
                a1 = fmaf(zf.z, e1.z, a1); a1 = fmaf(zf.w, e1.w, a1);
                a2 = fmaf(zf.x, e2.x, a2); a2 = fmaf(zf.y, e2.y, a2);
                a2 = fmaf(zf.z, e2.z, a2); a2 = fmaf(zf.w, e2.w, a2);
                float sx = zf.x * zf.x, sy = zf.y * zf.y, sz = zf.z * zf.z, sw = zf.w * zf.w;
                switch (d4 & 3) {                  // q = d4&3, it ascending: bit-exact r2 chain
                    case 0: n0 += (double)sx; n0 += (double)sy; n0 += (double)sz; n0 += (double)sw; break;
                    case 1: n1 += (double)sx; n1 += (double)sy; n1 += (double)sz; n1 += (double)sw; break;
                    case 2: n2 += (double)sx; n2 += (double)sy; n2 += (double)sz; n2 += (double)sw; break;
                    default: n3 += (double)sx; n3 += (double)sy; n3 += (double)sz; n3 += (double)sw; break;
                }
            }
            float rn = (float)((n0 + n1) + (n2 + n3));
            float d1 = __fadd_rn(__fsub_rn(rn, __fmul_rn(2.0f, a1)), cvec[c1]);
            float d2 = __fadd_rn(__fsub_rn(rn, __fmul_rn(2.0f, a2)), cvec[c2]);
            unsigned long long p1v = ((unsigned long long)__float_as_uint(d1) << 32) | (unsigned)c1;
            unsigned long long p2v = ((unsigned long long)__float_as_uint(d2) << 32) | (unsigned)c2;
            rescored[row] = p1v < p2v ? p1v : p2v;
        }
        return;
    }

    // ---- full-rescan path (r17-verified): r2 chain, sa from staged zs ----
    int cnt = cnts[1];
    if (cnt > CAP_FULL) cnt = CAP_FULL;
    const int nu = ((cnt + 15) >> 4) << 2;   // ceil(cnt/16) row-groups x 4 code-splits
    for (int uu = blockIdx.x; uu < nu; uu += 256) {
        int rg = uu >> 2, ks = uu & 3;
        __syncthreads();
        if (tid < 16) {
            int fi = rg * 16 + tid;
            srow[tid] = fulllist[fi < cnt ? fi : 0];
        }
        __syncthreads();
#pragma unroll
        for (int i = 0; i < 4; ++i) {
            int u = i * 256 + tid;
            int r = u >> 6, d4 = u & 63;
            *(float4*)&zs[r][d4 * 4] = *(const float4*)&z[(size_t)srow[r] * D_DIM + d4 * 4];
        }
        __syncthreads();
        if (tid < 64) {
            int r = tid >> 2, q = tid & 3;
            double acc = 0.0;
#pragma unroll 4
            for (int it = 0; it < 16; ++it) {
                float4 v = *(const float4*)&zs[r][(q + 4 * it) * 4];
                float a = v.x * v.x, b = v.y * v.y, c = v.z * v.z, d = v.w * v.w;
                acc += (double)a; acc += (double)b; acc += (double)c; acc += (double)d;
            }
            acc += __shfl_xor(acc, 1);
            acc += __shfl_xor(acc, 2);
            if (q == 0) sa[r] = (float)acc;
        }
        __syncthreads();

        const int c0 = ks * 1024 + tid;
        float acc[16][4];
#pragma unroll
        for (int r = 0; r < 16; ++r)
#pragma unroll
            for (int j = 0; j < 4; ++j) acc[r][j] = 0.f;

        for (int ch = 0; ch < 8; ++ch) {
#pragma unroll
            for (int q = 0; q < 8; ++q) {
                float4 e0 = *(const float4*)&emb[(size_t)(c0      ) * D_DIM + ch * 32 + q * 4];
                float4 e1 = *(const float4*)&emb[(size_t)(c0 + 256) * D_DIM + ch * 32 + q * 4];
                float4 e2 = *(const float4*)&emb[(size_t)(c0 + 512) * D_DIM + ch * 32 + q * 4];
                float4 e3 = *(const float4*)&emb[(size_t)(c0 + 768) * D_DIM + ch * 32 + q * 4];
#pragma unroll
                for (int r = 0; r < 16; ++r) {
                    float4 zf = *(const float4*)&zs[r][ch * 32 + q * 4];
                    acc[r][0] = fmaf(zf.x, e0.x, acc[r][0]);
                    acc[r][0] = fmaf(zf.y, e0.y, acc[r][0]);
                    acc[r][0] = fmaf(zf.z, e0.z, acc[r][0]);
                    acc[r][0] = fmaf(zf.w, e0.w, acc[r][0]);
                    acc[r][1] = fmaf(zf.x, e1.x, acc[r][1]);
                    acc[r][1] = fmaf(zf.y, e1.y, acc[r][1]);
                    acc[r][1] = fmaf(zf.z, e1.z, acc[r][1]);
                    acc[r][1] = fmaf(zf.w, e1.w, acc[r][1]);
                    acc[r][2] = fmaf(zf.x, e2.x, acc[r][2]);
                    acc[r][2] = fmaf(zf.y, e2.y, acc[r][2]);
                    acc[r][2] = fmaf(zf.z, e2.z, acc[r][2]);
                    acc[r][2] = fmaf(zf.w, e2.w, acc[r][2]);
                    acc[r][3] = fmaf(zf.x, e3.x, acc[r][3]);
                    acc[r][3] = fmaf(zf.y, e3.y, acc[r][3]);
                    acc[r][3] = fmaf(zf.z, e3.z, acc[r][3]);
                    acc[r][3] = fmaf(zf.w, e3.w, acc[r][3]);
                }
            }
        }
        const float ck0 = cvec[c0], ck1 = cvec[c0 + 256];
        const float ck2 = cvec[c0 + 512], ck3 = cvec[c0 + 768];
#pragma unroll
        for (int r = 0; r < 16; ++r) {
            float d0 = __fadd_rn(__fsub_rn(sa[r], __fmul_rn(2.0f, acc[r][0])), ck0);
            float d1 = __fadd_rn(__fsub_rn(sa[r], __fmul_rn(2.0f, acc[r][1])), ck1);
            float d2 = __fadd_rn(__fsub_rn(sa[r], __fmul_rn(2.0f, acc[r][2])), ck2);
            float d3 = __fadd_rn(__fsub_rn(sa[r], __fmul_rn(2.0f, acc[r][3])), ck3);
            unsigned long long p0 = ((unsigned long long)__float_as_uint(d0) << 32) | (unsigned)(c0);
            unsigned long long p1 = ((unsigned long long)__float_as_uint(d1) << 32) | (unsigned)(c0 + 256);
            unsigned long long p2 = ((unsigned long long)__float_as_uint(d2) << 32) | (unsigned)(c0 + 512);
            unsigned long long p3 = ((unsigned long long)__float_as_uint(d3) << 32) | (unsigned)(c0 + 768);
            unsigned long long pa = p0 < p1 ? p0 : p1;
            unsigned long long pb = p2 < p3 ? p2 : p3;
            unsigned long long pm = pa < pb ? pa : pb;
            for (int msk = 32; msk >= 1; msk >>= 1) {
                unsigned long long qv = __shfl_xor(pm, msk);
                pm = qv < pm ? qv : pm;
            }
            if ((tid & 63) == 0) atomicMin(&rescored[srow[r]], pm);
        }
    }
}

// ---------------- writeback: 16 rows/block, phase-split loads for ILP (r9-verified math) ----------------
__global__ __launch_bounds__(256) void writeback_kernel(
        const float* __restrict__ z, const float* __restrict__ emb,
        const unsigned long long* __restrict__ rescored,
        float* __restrict__ out_idx, float* __restrict__ out0,
        double* __restrict__ partials) {
    const int tid = threadIdx.x;
    const int base = blockIdx.x * 16;
    const int d4 = tid & 63;
    int rows[4], idx[4];
    unsigned long long rv[4];
#pragma unroll
    for (int g = 0; g < 4; ++g) {
        rows[g] = base + g * 4 + (tid >> 6);
        rv[g] = rescored[rows[g]];
    }
#pragma unroll
    for (int g = 0; g < 4; ++g) {
        if (rv[g] != ~0ull) {
            idx[g] = (int)(unsigned)(rv[g] & 0xffffffffull);
            if (d4 == 0) out_idx[rows[g]] = (float)idx[g];
        } else {
            idx[g] = (int)out_idx[rows[g]];
        }
    }
    double acc = 0.0;
#pragma unroll
    for (int g = 0; g < 4; ++g) {
        float4 q4 = *(const float4*)&emb[(size_t)idx[g] * D_DIM + d4 * 4];
        float4 z4 = *(const float4*)&z[(size_t)rows[g] * D_DIM + d4 * 4];
        float4 o;
        float dx;
        dx = q4.x - z4.x; o.x = z4.x + dx; acc += (double)dx * dx;
        dx = q4.y - z4.y; o.y = z4.y + dx; acc += (double)dx * dx;
        dx = q4.z - z4.z; o.z = z4.z + dx; acc += (double)dx * dx;
        dx = q4.w - z4.w; o.w = z4.w + dx; acc += (double)dx * dx;
        *(float4*)&out0[(size_t)rows[g] * D_DIM + d4 * 4] = o;
    }
    for (int m = 32; m >= 1; m >>= 1) acc += __shfl_xor(acc, m);
    __shared__ double sd[4];
    if ((tid & 63) == 0) sd[tid >> 6] = acc;
    __syncthreads();
    if (tid == 0) partials[blockIdx.x] = (sd[0] + sd[1]) + (sd[2] + sd[3]);
}

__global__ void finalize_kernel(const double* __restrict__ partials, float* __restrict__ out_loss) {
    __shared__ double sd[256];
    const int tid = threadIdx.x;
    double a = 0.0;
    for (int i = tid; i < 4096; i += 256) a += partials[i];
    sd[tid] = a;
    __syncthreads();
    for (int s = 128; s > 0; s >>= 1) {
        if (tid < s) sd[tid] += sd[tid + s];
        __syncthreads();
    }
    if (tid == 0) {
        double m = sd[0] / 16777216.0;
        out_loss[0] = (float)(m + 0.25 * m);
    }
}

extern "C" void kernel_launch(void* const* d_in, const int* in_sizes, int n_in,
                              void* d_out, int out_size, void* d_ws, size_t ws_size,
                              hipStream_t stream) {
    const float* z = (const float*)d_in[0];
    const float* emb = (const float*)d_in[1];
    float* out0 = (float*)d_out;
    float* out_loss = out0 + (size_t)N_ROWS * D_DIM;
    float* out_idx = out_loss + 1;

    char* ws = (char*)d_ws;
    float* cvec = (float*)(ws + 262144);
    unsigned short* emb_perm = (unsigned short*)(ws + 278528);
    int* cnts = (int*)(ws + 2375680);
    int* fulllist = (int*)(ws + 2375936);
    unsigned long long* duellist = (unsigned long long*)(ws + 2408704);
    unsigned long long* rescored = (unsigned long long*)(ws + 2605312);
    double* partials = (double*)(ws + 3129600);

    // 32 MB z_perm scratch inside d_out (fully overwritten by writeback_kernel)
    unsigned short* z_perm = (unsigned short*)d_out;

    cvt_all_kernel<<<8768, 256, 0, stream>>>(z, emb, z_perm, emb_perm, cvec, cnts, rescored);
    phaseB_kernel<<<512, 256, 0, stream>>>(z_perm, emb_perm, cvec, out_idx, cnts, fulllist, duellist);
    refine_kernel<<<320, 256, 0, stream>>>(z, emb, cvec, cnts, fulllist, duellist, rescored);
    writeback_kernel<<<N_ROWS / 16, 256, 0, stream>>>(z, emb, rescored, out_idx, out0, partials);
    finalize_kernel<<<1, 256, 0, stream>>>(partials, out_loss);
}